// Round 7
// baseline (1247.729 us; speedup 1.0000x reference)
//
#include <hip/hip_runtime.h>
#include <hip/hip_fp16.h>
#include <math.h>

#define NND 100000
#define NED 800000
#define NLAY 3
#define BSH 9                      // 512 nodes per bucket
#define NBKT ((NND + 511) / 512)   // 196
#define ASTR 68                    // acc LDS row stride (floats); mult of 4 for b128, 17 f4 -> conflict-free
static constexpr float LNEPS = 1e-5f;

typedef __attribute__((ext_vector_type(8))) short short8;
typedef __attribute__((ext_vector_type(4))) float floatx4;

// fp32 -> bf16 round-to-nearest-even
__device__ __forceinline__ short f2bf(float f) {
    unsigned u = __float_as_uint(f);
    u += 0x7fffu + ((u >> 16) & 1u);
    return (short)(u >> 16);
}

// unpack 8 consecutive halfs (16B) into fp32
__device__ __forceinline__ void load_h8(const __half* p, float* f) {
    uint4 v = *(const uint4*)p;
    unsigned a[4] = {v.x, v.y, v.z, v.w};
#pragma unroll
    for (int k = 0; k < 4; k++) {
        __half2 h = *(__half2*)&a[k];
        float2 g = __half22float2(h);
        f[2 * k] = g.x; f[2 * k + 1] = g.y;
    }
}

// ---------------- init: zero bucket counts + reduction accumulators ----------------
__global__ void k_init(int* __restrict__ bcnt, float* __restrict__ rsum, unsigned* __restrict__ rmax) {
    int gt = blockIdx.x * blockDim.x + threadIdx.x;
    if (gt < NBKT) bcnt[gt] = 0;
    if (gt >= 256 && gt < 320) { rsum[gt - 256] = 0.f; rmax[gt - 256] = 0u; }
}

// ---------------- embed: x[n] = table[type[n]] ----------------
__global__ void k_embed(const int* __restrict__ ty, const float4* __restrict__ tab, float4* __restrict__ x) {
    int t = blockIdx.x * blockDim.x + threadIdx.x;  // one float4 per thread
    if (t >= NND * 16) return;
    int n = t >> 4, q = t & 15;
    x[t] = tab[ty[n] * 16 + q];
}

// ---------------- bucket histogram (LDS-staged, no random global atomics) ----------------
__global__ __launch_bounds__(256) void k_bhist(const int2* __restrict__ e, int* __restrict__ bcnt) {
    __shared__ int h[NBKT];
    for (int i = threadIdx.x; i < NBKT; i += 256) h[i] = 0;
    __syncthreads();
    int stride = gridDim.x * 256;
    for (int i = blockIdx.x * 256 + threadIdx.x; i < NED; i += stride)
        atomicAdd(&h[((unsigned)e[i].y) >> BSH], 1);
    __syncthreads();
    for (int i = threadIdx.x; i < NBKT; i += 256) if (h[i]) atomicAdd(&bcnt[i], h[i]);
}

// ---------------- scan bucket counts -> bucket bases + global tails ----------------
__global__ void k_bbase(const int* __restrict__ bcnt, int* __restrict__ bbase, int* __restrict__ gtail) {
    __shared__ int p[256];
    int t = threadIdx.x;
    int v = (t < NBKT) ? bcnt[t] : 0;
    p[t] = v; __syncthreads();
    for (int off = 1; off < 256; off <<= 1) {
        int u = (t >= off) ? p[t - off] : 0;
        __syncthreads();
        p[t] += u; __syncthreads();
    }
    if (t < NBKT) { int ex = p[t] - v; bbase[t] = ex; gtail[t] = ex; }
    if (t == NBKT - 1) bbase[NBKT] = p[t];   // == NED
}

// ---------------- bin edges by bucket into tmp (packed tgt<<32|src) ----------------
__global__ __launch_bounds__(256) void k_bscatter(const int2* __restrict__ e, int* __restrict__ gtail,
                                                  long long* __restrict__ tmp) {
    __shared__ int cnt[NBKT], chunk[NBKT], cur[NBKT];
    const int T = 4096;
    int ntile = (NED + T - 1) / T;
    for (int tile = blockIdx.x; tile < ntile; tile += gridDim.x) {
        int base = tile * T;
        int t = threadIdx.x;
        for (int i = t; i < NBKT; i += 256) { cnt[i] = 0; cur[i] = 0; }
        __syncthreads();
        int2 ed[16]; int bk[16];
#pragma unroll
        for (int i = 0; i < 16; i++) {
            int idx = base + i * 256 + t;
            if (idx < NED) {
                ed[i] = e[idx];
                bk[i] = ((unsigned)ed[i].y) >> BSH;
                atomicAdd(&cnt[bk[i]], 1);
            } else bk[i] = -1;
        }
        __syncthreads();
        for (int i = t; i < NBKT; i += 256) if (cnt[i]) chunk[i] = atomicAdd(&gtail[i], cnt[i]);
        __syncthreads();
#pragma unroll
        for (int i = 0; i < 16; i++) {
            if (bk[i] >= 0) {
                int r = atomicAdd(&cur[bk[i]], 1);
                tmp[(size_t)chunk[bk[i]] + r] =
                    ((long long)(unsigned)ed[i].y << 32) | (unsigned)ed[i].x;
            }
        }
        __syncthreads();
    }
}

// ---------------- prep: pre-swizzle weights into MFMA B-fragment layout (bf16) ----------------
__global__ void k_prep(const float* __restrict__ msg_w, const float* __restrict__ upd_w,
                       short* __restrict__ wmsg, short* __restrict__ wupd) {
    int t = blockIdx.x * blockDim.x + threadIdx.x;
    if (t >= 2 * NLAY * 8192) return;
    int which = t / (NLAY * 8192);
    int e = t % (NLAY * 8192);
    int l = e >> 13, idx = e & 8191;
    int j = idx & 7, lane = (idx >> 3) & 63, hi = idx >> 9;
    int lm = lane & 15, quad = lane >> 4;
    if (which == 0) {
        int ks = hi & 1, nt = hi >> 1;
        int n = nt * 16 + lm, k = ks * 32 + quad * 8 + j;
        float v = (n < 64) ? msg_w[(size_t)l * 8192 + k * 64 + n]
                           : msg_w[(size_t)l * 8192 + (64 + k) * 64 + (n - 64)];
        wmsg[e] = f2bf(v);
    } else {
        int ks = hi & 3, nt = hi >> 2;
        int n = nt * 16 + lm, k = ks * 32 + quad * 8 + j;
        wupd[e] = f2bf(upd_w[(size_t)l * 8192 + k * 64 + n]);
    }
}

// ---------------- initial P/Q (layer 0) from embedded x  (MFMA + LDS-transposed 16B stores) ----------------
__global__ __launch_bounds__(256) void k_pq(const float* __restrict__ x, const short* __restrict__ wb,
                                            const float* __restrict__ bg,
                                            __half* __restrict__ P16, __half* __restrict__ Q16) {
    __shared__ __half outs[64 * 136];
    int wv = threadIdx.x >> 6, lane = threadIdx.x & 63;
    int lm = lane & 15, quad = lane >> 4;
    int nbase = blockIdx.x * 64;
    int m = nbase + wv * 16 + lm;
    short8 a[2];
#pragma unroll
    for (int ks = 0; ks < 2; ks++) {
        float xv[8];
        if (m < NND) {
            float4 v0 = *(const float4*)(x + (size_t)m * 64 + ks * 32 + quad * 8);
            float4 v1 = *(const float4*)(x + (size_t)m * 64 + ks * 32 + quad * 8 + 4);
            xv[0] = v0.x; xv[1] = v0.y; xv[2] = v0.z; xv[3] = v0.w;
            xv[4] = v1.x; xv[5] = v1.y; xv[6] = v1.z; xv[7] = v1.w;
        } else {
#pragma unroll
            for (int j = 0; j < 8; j++) xv[j] = 0.f;
        }
        short8 av;
#pragma unroll
        for (int j = 0; j < 8; j++) av[j] = f2bf(xv[j]);
        a[ks] = av;
    }
    floatx4 acc[8];
#pragma unroll
    for (int nt = 0; nt < 8; nt++) acc[nt] = (floatx4){0.f, 0.f, 0.f, 0.f};
#pragma unroll
    for (int nt = 0; nt < 8; nt++) {
        short8 b0 = *(const short8*)(wb + (size_t)((nt * 2 + 0) * 64 + lane) * 8);
        short8 b1 = *(const short8*)(wb + (size_t)((nt * 2 + 1) * 64 + lane) * 8);
        acc[nt] = __builtin_amdgcn_mfma_f32_16x16x32_bf16(a[0], b0, acc[nt], 0, 0, 0);
        acc[nt] = __builtin_amdgcn_mfma_f32_16x16x32_bf16(a[1], b1, acc[nt], 0, 0, 0);
    }
    float bq[4];
#pragma unroll
    for (int nt = 0; nt < 4; nt++) bq[nt] = bg[nt * 16 + lm];
#pragma unroll
    for (int reg = 0; reg < 4; reg++) {
        int rown = wv * 16 + quad * 4 + reg;
#pragma unroll
        for (int nt = 0; nt < 4; nt++)
            outs[rown * 136 + nt * 16 + lm] = __float2half(acc[nt][reg]);
#pragma unroll
        for (int nt = 4; nt < 8; nt++)
            outs[rown * 136 + 64 + (nt - 4) * 16 + lm] = __float2half(acc[nt][reg] + bq[nt - 4]);
    }
    __syncthreads();
    int t = threadIdx.x;
#pragma unroll
    for (int r = 0; r < 4; r++) {
        int s = r * 256 + t;
        int node = s >> 4, seg = s & 15;
        int gn = nbase + node;
        if (gn < NND) {
            uint4 v = *(const uint4*)(outs + node * 136 + seg * 8);
            __half* dst = (seg < 8) ? (P16 + (size_t)gn * 64 + seg * 8)
                                    : (Q16 + (size_t)gn * 64 + (seg - 8) * 8);
            *(uint4*)dst = v;
        }
    }
}

// ---------------- fused layer: edge-parallel gather (LDS f32 atomics) + MFMA update + next-layer P/Q ----------------
// One block per 512-node bucket. tmp holds the bucket's edges (binned by k_bscatter).
__global__ __launch_bounds__(512) void k_layer(
    float* __restrict__ x,
    const __half* __restrict__ Pin, const __half* __restrict__ Qin,
    const long long* __restrict__ tmp, const int* __restrict__ bbase,
    const short* __restrict__ wu, const float* __restrict__ ub,
    const float* __restrict__ lg, const float* __restrict__ lb,
    const short* __restrict__ wm, const float* __restrict__ bgn,
    __half* __restrict__ Pout, __half* __restrict__ Qout, int last)
{
    __shared__ float4 accv[512 * (ASTR / 4)];      // 512 x 68 floats = 139,264 B
    __shared__ int deg_s[512];
    float* acc_s = (float*)accv;
    int b = blockIdx.x, t = threadIdx.x;
    int node0 = b << BSH;

    // zero
#pragma unroll
    for (int i = 0; i < 512 * (ASTR / 4) / 512; i++)
        accv[i * 512 + t] = make_float4(0.f, 0.f, 0.f, 0.f);
    deg_s[t] = 0;
    __syncthreads();

    // ---- phase 1: edge-parallel gather (8 lanes per edge, 8 feats per lane) ----
    int ebase = bbase[b], eend = bbase[b + 1];
    int g = t >> 3, f8 = t & 7, c0 = f8 * 8;
    for (int ei = ebase + g; ei < eend; ei += 64) {
        long long pk = tmp[ei];
        int tgt = (int)(pk >> 32);
        int src = (int)(pk & 0xffffffffll);
        int tl = tgt - node0;
        float p[8], q[8];
        load_h8(Pin + (size_t)src * 64 + c0, p);
        load_h8(Qin + (size_t)tgt * 64 + c0, q);
        float* ap = acc_s + tl * ASTR + c0;
#pragma unroll
        for (int k = 0; k < 8; k++) atomicAdd(&ap[k], fmaxf(p[k] + q[k], 0.f));
        if (f8 == 0) atomicAdd(&deg_s[tl], 1);
    }
    __syncthreads();

    // ---- phase 2+3: per-wave 16-node tiles ----
    int w = t >> 6, lane = t & 63;
    int lm = lane & 15, quad = lane >> 4;
    float ubv[4], lgv[4], lbv[4], bq[4];
#pragma unroll
    for (int nt = 0; nt < 4; nt++) {
        int col = nt * 16 + lm;
        ubv[nt] = ub[col]; lgv[nt] = lg[col]; lbv[nt] = lb[col];
        bq[nt] = bgn[col];
    }
    __half* hs = (__half*)acc_s;    // half view, row stride 136

    for (int ti = 0; ti < 4; ti++) {
        int tile = w * 4 + ti;
        int bm = tile * 16 + lm;
        int gm = node0 + bm;
        bool okm = gm < NND;
        short8 a[4];
#pragma unroll
        for (int ks = 0; ks < 2; ks++) {
            float xv[8];
            if (okm) {
                float4 v0 = *(const float4*)(x + (size_t)gm * 64 + ks * 32 + quad * 8);
                float4 v1 = *(const float4*)(x + (size_t)gm * 64 + ks * 32 + quad * 8 + 4);
                xv[0] = v0.x; xv[1] = v0.y; xv[2] = v0.z; xv[3] = v0.w;
                xv[4] = v1.x; xv[5] = v1.y; xv[6] = v1.z; xv[7] = v1.w;
            } else {
#pragma unroll
                for (int j = 0; j < 8; j++) xv[j] = 0.f;
            }
            short8 av;
#pragma unroll
            for (int j = 0; j < 8; j++) av[j] = f2bf(xv[j]);
            a[ks] = av;
        }
        float inv = 1.f / fmaxf((float)deg_s[bm], 1.f);
#pragma unroll
        for (int ks = 2; ks < 4; ks++) {
            const float* p = acc_s + bm * ASTR + (ks - 2) * 32 + quad * 8;
            float4 v0 = *(const float4*)p;
            float4 v1 = *(const float4*)(p + 4);
            float xv[8] = {v0.x * inv, v0.y * inv, v0.z * inv, v0.w * inv,
                           v1.x * inv, v1.y * inv, v1.z * inv, v1.w * inv};
            short8 av;
#pragma unroll
            for (int j = 0; j < 8; j++) av[j] = f2bf(xv[j]);
            a[ks] = av;
        }
        floatx4 c4[4];
#pragma unroll
        for (int nt = 0; nt < 4; nt++) c4[nt] = (floatx4){0.f, 0.f, 0.f, 0.f};
#pragma unroll
        for (int nt = 0; nt < 4; nt++) {
#pragma unroll
            for (int ks = 0; ks < 4; ks++) {
                short8 bb = *(const short8*)(wu + (size_t)((nt * 4 + ks) * 64 + lane) * 8);
                c4[nt] = __builtin_amdgcn_mfma_f32_16x16x32_bf16(a[ks], bb, c4[nt], 0, 0, 0);
            }
        }
        // epilogue: relu+bias, residual, LN; write x (global) + new-x (LDS, for phase 3)
#pragma unroll
        for (int reg = 0; reg < 4; reg++) {
            int rown = tile * 16 + quad * 4 + reg;
            int gn = node0 + rown;
            bool ok = gn < NND;
            float h[4];
#pragma unroll
            for (int nt = 0; nt < 4; nt++) {
                float xv = ok ? x[(size_t)gn * 64 + nt * 16 + lm] : 0.f;
                float u = fmaxf(c4[nt][reg] + ubv[nt], 0.f);
                h[nt] = u + xv;
            }
            float s1 = h[0] + h[1] + h[2] + h[3];
            float s2 = h[0] * h[0] + h[1] * h[1] + h[2] * h[2] + h[3] * h[3];
#pragma unroll
            for (int off = 1; off < 16; off *= 2) {
                s1 += __shfl_xor(s1, off);
                s2 += __shfl_xor(s2, off);
            }
            float mu = s1 * (1.f / 64.f);
            float var = s2 * (1.f / 64.f) - mu * mu;
            float rs = rsqrtf(var + LNEPS);
#pragma unroll
            for (int nt = 0; nt < 4; nt++) {
                float res = (h[nt] - mu) * rs * lgv[nt] + lbv[nt];
                if (ok) x[(size_t)gn * 64 + nt * 16 + lm] = res;
                acc_s[rown * ASTR + nt * 16 + lm] = res;   // overwrite agg rows (same-wave only)
            }
        }
        if (!last) {
            // ---- phase 3: next-layer P/Q for this tile; A-frags from LDS new-x ----
            short8 na[2];
#pragma unroll
            for (int ks = 0; ks < 2; ks++) {
                const float* p = acc_s + bm * ASTR + ks * 32 + quad * 8;
                float4 v0 = *(const float4*)p;
                float4 v1 = *(const float4*)(p + 4);
                float xv[8] = {v0.x, v0.y, v0.z, v0.w, v1.x, v1.y, v1.z, v1.w};
                short8 av;
#pragma unroll
                for (int j = 0; j < 8; j++) av[j] = f2bf(xv[j]);
                na[ks] = av;
            }
            floatx4 c8[8];
#pragma unroll
            for (int nt = 0; nt < 8; nt++) c8[nt] = (floatx4){0.f, 0.f, 0.f, 0.f};
#pragma unroll
            for (int nt = 0; nt < 8; nt++) {
                short8 b0 = *(const short8*)(wm + (size_t)((nt * 2 + 0) * 64 + lane) * 8);
                short8 b1 = *(const short8*)(wm + (size_t)((nt * 2 + 1) * 64 + lane) * 8);
                c8[nt] = __builtin_amdgcn_mfma_f32_16x16x32_bf16(na[0], b0, c8[nt], 0, 0, 0);
                c8[nt] = __builtin_amdgcn_mfma_f32_16x16x32_bf16(na[1], b1, c8[nt], 0, 0, 0);
            }
            // stage C-layout halves into this tile's rows, then vector-store
#pragma unroll
            for (int reg = 0; reg < 4; reg++) {
                int rown = tile * 16 + quad * 4 + reg;
#pragma unroll
                for (int nt = 0; nt < 4; nt++)
                    hs[rown * (2 * ASTR) + nt * 16 + lm] = __float2half(c8[nt][reg]);
#pragma unroll
                for (int nt = 4; nt < 8; nt++)
                    hs[rown * (2 * ASTR) + 64 + (nt - 4) * 16 + lm] = __float2half(c8[nt][reg] + bq[nt - 4]);
            }
#pragma unroll
            for (int pass = 0; pass < 4; pass++) {
                int idx = pass * 64 + lane;
                int nd = idx >> 4, seg = idx & 15;
                int rown = tile * 16 + nd;
                int gn = node0 + rown;
                if (gn < NND) {
                    uint4 v = *(const uint4*)(hs + rown * (2 * ASTR) + seg * 8);
                    __half* dst = (seg < 8) ? (Pout + (size_t)gn * 64 + seg * 8)
                                            : (Qout + (size_t)gn * 64 + (seg - 8) * 8);
                    *(uint4*)dst = v;
                }
            }
        }
    }
}

// ---------------- final reduce: column mean + max ----------------
__global__ void k_reduce(const float* __restrict__ x, float* __restrict__ rsum, unsigned* __restrict__ rmax) {
    __shared__ float sb[256];
    __shared__ float mb[256];
    int t = threadIdx.x;
    int j = t & 63, g = t >> 6;
    float s = 0.f, m = -3.402823466e38f;
    for (int r = blockIdx.x * 4 + g; r < NND; r += gridDim.x * 4) {
        float v = x[r * 64 + j];
        s += v;
        m = fmaxf(m, v);
    }
    sb[t] = s; mb[t] = m; __syncthreads();
    if (t < 64) {
        s = sb[t] + sb[t + 64] + sb[t + 128] + sb[t + 192];
        m = fmaxf(fmaxf(mb[t], mb[t + 64]), fmaxf(mb[t + 128], mb[t + 192]));
        atomicAdd(&rsum[j], s);
        unsigned bb = __float_as_uint(m);
        unsigned enc = (bb & 0x80000000u) ? ~bb : (bb | 0x80000000u);
        atomicMax(&rmax[j], enc);
    }
}

__global__ void k_fin(const float* __restrict__ rsum, const unsigned* __restrict__ rmax, float* __restrict__ out) {
    int t = threadIdx.x;
    if (t < 64) {
        out[t] = rsum[t] * (1.f / (float)NND);
    } else if (t < 128) {
        unsigned u = rmax[t - 64];
        unsigned bb = (u & 0x80000000u) ? (u & 0x7fffffffu) : ~u;
        out[t] = __uint_as_float(bb);
    }
}

extern "C" void kernel_launch(void* const* d_in, const int* in_sizes, int n_in,
                              void* d_out, int out_size, void* d_ws, size_t ws_size,
                              hipStream_t stream) {
    const int* ty      = (const int*)d_in[0];
    const int* ed      = (const int*)d_in[1];
    const float* tab   = (const float*)d_in[2];
    const float* msg_w = (const float*)d_in[3];
    const float* msg_b = (const float*)d_in[4];
    const float* upd_w = (const float*)d_in[5];
    const float* upd_b = (const float*)d_in[6];
    const float* ln_g  = (const float*)d_in[7];
    const float* ln_b  = (const float*)d_in[8];
    float* out = (float*)d_out;

    char* w = (char*)d_ws;
    auto alloc = [&](size_t sz) { char* p = w; w += (sz + 255) & ~(size_t)255; return p; };
    float* x       = (float*)alloc((size_t)NND * 64 * 4);
    __half* P0     = (__half*)alloc((size_t)NND * 64 * 2);
    __half* Q0     = (__half*)alloc((size_t)NND * 64 * 2);
    __half* P1     = (__half*)alloc((size_t)NND * 64 * 2);
    __half* Q1     = (__half*)alloc((size_t)NND * 64 * 2);
    long long* tmp = (long long*)alloc((size_t)NED * 8);
    int* bcnt      = (int*)alloc(256 * 4);
    int* bbase     = (int*)alloc(256 * 4);
    int* gtail     = (int*)alloc(256 * 4);
    float* rsum    = (float*)alloc(64 * 4);
    unsigned* rmax = (unsigned*)alloc(64 * 4);
    short* wmsg    = (short*)alloc((size_t)NLAY * 8192 * 2);
    short* wupd    = (short*)alloc((size_t)NLAY * 8192 * 2);

    k_init<<<2, 256, 0, stream>>>(bcnt, rsum, rmax);
    k_prep<<<(2 * NLAY * 8192 + 255) / 256, 256, 0, stream>>>(msg_w, upd_w, wmsg, wupd);
    k_embed<<<(NND * 16 + 255) / 256, 256, 0, stream>>>(ty, (const float4*)tab, (float4*)x);
    k_bhist<<<256, 256, 0, stream>>>((const int2*)ed, bcnt);
    k_bbase<<<1, 256, 0, stream>>>(bcnt, bbase, gtail);
    k_bscatter<<<(NED + 4095) / 4096, 256, 0, stream>>>((const int2*)ed, gtail, tmp);
    k_pq<<<(NND + 63) / 64, 256, 0, stream>>>(x, wmsg, msg_b, P0, Q0);

    // layer 0: in P0/Q0 -> out P1/Q1 ; layer 1: in P1/Q1 -> out P0/Q0 ; layer 2: in P0/Q0, last
    k_layer<<<NBKT, 512, 0, stream>>>(x, P0, Q0, tmp, bbase,
                                      wupd + 0 * 8192, upd_b + 0, ln_g + 0, ln_b + 0,
                                      wmsg + 1 * 8192, msg_b + 64, P1, Q1, 0);
    k_layer<<<NBKT, 512, 0, stream>>>(x, P1, Q1, tmp, bbase,
                                      wupd + 1 * 8192, upd_b + 64, ln_g + 64, ln_b + 64,
                                      wmsg + 2 * 8192, msg_b + 128, P0, Q0, 0);
    k_layer<<<NBKT, 512, 0, stream>>>(x, P0, Q0, tmp, bbase,
                                      wupd + 2 * 8192, upd_b + 128, ln_g + 128, ln_b + 128,
                                      wmsg + 2 * 8192, msg_b + 128, P1, Q1, 1);

    k_reduce<<<256, 256, 0, stream>>>(x, rsum, rmax);
    k_fin<<<1, 128, 0, stream>>>(rsum, rmax, out);
}

// Round 8
// 297.500 us; speedup vs baseline: 4.1940x; 4.1940x over previous
//
#include <hip/hip_runtime.h>
#include <hip/hip_fp16.h>
#include <math.h>

#define NND 100000
#define NED 800000
#define NLAY 3
#define BSH 9                      // 512 nodes per bucket
#define NBKT ((NND + 511) / 512)   // 196
static constexpr float LNEPS = 1e-5f;

typedef __attribute__((ext_vector_type(8))) short short8;
typedef __attribute__((ext_vector_type(4))) float floatx4;

// fp32 -> bf16 round-to-nearest-even
__device__ __forceinline__ short f2bf(float f) {
    unsigned u = __float_as_uint(f);
    u += 0x7fffu + ((u >> 16) & 1u);
    return (short)(u >> 16);
}

// unpack 8 consecutive halfs (16B) into fp32
__device__ __forceinline__ void load_h8(const __half* p, float* f) {
    uint4 v = *(const uint4*)p;
    unsigned a[4] = {v.x, v.y, v.z, v.w};
#pragma unroll
    for (int k = 0; k < 4; k++) {
        __half2 h = *(__half2*)&a[k];
        float2 g = __half22float2(h);
        f[2 * k] = g.x; f[2 * k + 1] = g.y;
    }
}

// ---------------- init: zero bucket counts + reduction accumulators ----------------
__global__ void k_init(int* __restrict__ bcnt, float* __restrict__ rsum, unsigned* __restrict__ rmax) {
    int gt = blockIdx.x * blockDim.x + threadIdx.x;
    if (gt < NBKT) bcnt[gt] = 0;
    if (gt >= 256 && gt < 320) { rsum[gt - 256] = 0.f; rmax[gt - 256] = 0u; }
}

// ---------------- embed: x[n] = table[type[n]] ----------------
__global__ void k_embed(const int* __restrict__ ty, const float4* __restrict__ tab, float4* __restrict__ x) {
    int t = blockIdx.x * blockDim.x + threadIdx.x;  // one float4 per thread
    if (t >= NND * 16) return;
    int n = t >> 4, q = t & 15;
    x[t] = tab[ty[n] * 16 + q];
}

// ---------------- bucket histogram (LDS-staged, no random global atomics) ----------------
__global__ __launch_bounds__(256) void k_bhist(const int2* __restrict__ e, int* __restrict__ bcnt) {
    __shared__ int h[NBKT];
    for (int i = threadIdx.x; i < NBKT; i += 256) h[i] = 0;
    __syncthreads();
    int stride = gridDim.x * 256;
    for (int i = blockIdx.x * 256 + threadIdx.x; i < NED; i += stride)
        atomicAdd(&h[((unsigned)e[i].y) >> BSH], 1);
    __syncthreads();
    for (int i = threadIdx.x; i < NBKT; i += 256) if (h[i]) atomicAdd(&bcnt[i], h[i]);
}

// ---------------- scan bucket counts -> bucket bases + global tails ----------------
__global__ void k_bbase(const int* __restrict__ bcnt, int* __restrict__ bbase, int* __restrict__ gtail) {
    __shared__ int p[256];
    int t = threadIdx.x;
    int v = (t < NBKT) ? bcnt[t] : 0;
    p[t] = v; __syncthreads();
    for (int off = 1; off < 256; off <<= 1) {
        int u = (t >= off) ? p[t - off] : 0;
        __syncthreads();
        p[t] += u; __syncthreads();
    }
    if (t < NBKT) { int ex = p[t] - v; bbase[t] = ex; gtail[t] = ex; }
    if (t == NBKT - 1) bbase[NBKT] = p[t];   // == NED
}

// ---------------- bin edges by bucket into tmp (packed tgt<<32|src) ----------------
__global__ __launch_bounds__(256) void k_bscatter(const int2* __restrict__ e, int* __restrict__ gtail,
                                                  long long* __restrict__ tmp) {
    __shared__ int cnt[NBKT], chunk[NBKT], cur[NBKT];
    const int T = 4096;
    int ntile = (NED + T - 1) / T;
    for (int tile = blockIdx.x; tile < ntile; tile += gridDim.x) {
        int base = tile * T;
        int t = threadIdx.x;
        for (int i = t; i < NBKT; i += 256) { cnt[i] = 0; cur[i] = 0; }
        __syncthreads();
        int2 ed[16]; int bk[16];
#pragma unroll
        for (int i = 0; i < 16; i++) {
            int idx = base + i * 256 + t;
            if (idx < NED) {
                ed[i] = e[idx];
                bk[i] = ((unsigned)ed[i].y) >> BSH;
                atomicAdd(&cnt[bk[i]], 1);
            } else bk[i] = -1;
        }
        __syncthreads();
        for (int i = t; i < NBKT; i += 256) if (cnt[i]) chunk[i] = atomicAdd(&gtail[i], cnt[i]);
        __syncthreads();
#pragma unroll
        for (int i = 0; i < 16; i++) {
            if (bk[i] >= 0) {
                int r = atomicAdd(&cur[bk[i]], 1);
                tmp[(size_t)chunk[bk[i]] + r] =
                    ((long long)(unsigned)ed[i].y << 32) | (unsigned)ed[i].x;
            }
        }
        __syncthreads();
    }
}

// ---------------- per-bucket: degree hist + scan -> row, place srcs (single-CU window) ----------------
__global__ __launch_bounds__(512) void k_bfinish(const long long* __restrict__ tmp, const int* __restrict__ bbase,
                                                 int* __restrict__ row, int* __restrict__ srcs) {
    __shared__ int ld[512];
    __shared__ int lcur[512];
    int b = blockIdx.x, t = threadIdx.x;
    int node0 = b << BSH;
    int nn = min(512, NND - node0);
    int ebase = bbase[b], eend = bbase[b + 1];
    ld[t] = 0;
    __syncthreads();
    for (int i = ebase + t; i < eend; i += 512) {
        int tgt = (int)(tmp[i] >> 32);
        atomicAdd(&ld[tgt - node0], 1);
    }
    __syncthreads();
    int v = ld[t];
    for (int off = 1; off < 512; off <<= 1) {
        int u = (t >= off) ? ld[t - off] : 0;
        __syncthreads();
        ld[t] += u;
        __syncthreads();
    }
    int exc = ld[t] - v;             // exclusive prefix of degrees
    if (t < nn) row[node0 + t] = ebase + exc;
    lcur[t] = exc;
    __syncthreads();
    for (int i = ebase + t; i < eend; i += 512) {
        long long pk = tmp[i];
        int tgt = (int)(pk >> 32);
        int src = (int)(pk & 0xffffffffll);
        int p = atomicAdd(&lcur[tgt - node0], 1);
        srcs[ebase + p] = src;
    }
    if (b == NBKT - 1 && t == 0) row[NND] = NED;
}

// ---------------- prep: pre-swizzle weights into MFMA B-fragment layout (bf16) ----------------
__global__ void k_prep(const float* __restrict__ msg_w, const float* __restrict__ upd_w,
                       short* __restrict__ wmsg, short* __restrict__ wupd) {
    int t = blockIdx.x * blockDim.x + threadIdx.x;
    if (t >= 2 * NLAY * 8192) return;
    int which = t / (NLAY * 8192);
    int e = t % (NLAY * 8192);
    int l = e >> 13, idx = e & 8191;
    int j = idx & 7, lane = (idx >> 3) & 63, hi = idx >> 9;
    int lm = lane & 15, quad = lane >> 4;
    if (which == 0) {
        int ks = hi & 1, nt = hi >> 1;
        int n = nt * 16 + lm, k = ks * 32 + quad * 8 + j;
        float v = (n < 64) ? msg_w[(size_t)l * 8192 + k * 64 + n]
                           : msg_w[(size_t)l * 8192 + (64 + k) * 64 + (n - 64)];
        wmsg[e] = f2bf(v);
    } else {
        int ks = hi & 3, nt = hi >> 2;
        int n = nt * 16 + lm, k = ks * 32 + quad * 8 + j;
        wupd[e] = f2bf(upd_w[(size_t)l * 8192 + k * 64 + n]);
    }
}

// ---------------- P16 = half(x@Ws) ; Q16 = half(x@Wt + b)  (MFMA + LDS-transposed 16B stores) ----------------
__global__ __launch_bounds__(256) void k_pq(const float* __restrict__ x, const short* __restrict__ wb,
                                            const float* __restrict__ bg,
                                            __half* __restrict__ P16, __half* __restrict__ Q16) {
    __shared__ __half outs[64 * 136];
    int wv = threadIdx.x >> 6, lane = threadIdx.x & 63;
    int lm = lane & 15, quad = lane >> 4;
    int nbase = blockIdx.x * 64;
    int m = nbase + wv * 16 + lm;
    short8 a[2];
#pragma unroll
    for (int ks = 0; ks < 2; ks++) {
        float xv[8];
        if (m < NND) {
            float4 v0 = *(const float4*)(x + (size_t)m * 64 + ks * 32 + quad * 8);
            float4 v1 = *(const float4*)(x + (size_t)m * 64 + ks * 32 + quad * 8 + 4);
            xv[0] = v0.x; xv[1] = v0.y; xv[2] = v0.z; xv[3] = v0.w;
            xv[4] = v1.x; xv[5] = v1.y; xv[6] = v1.z; xv[7] = v1.w;
        } else {
#pragma unroll
            for (int j = 0; j < 8; j++) xv[j] = 0.f;
        }
        short8 av;
#pragma unroll
        for (int j = 0; j < 8; j++) av[j] = f2bf(xv[j]);
        a[ks] = av;
    }
    floatx4 acc[8];
#pragma unroll
    for (int nt = 0; nt < 8; nt++) acc[nt] = (floatx4){0.f, 0.f, 0.f, 0.f};
#pragma unroll
    for (int nt = 0; nt < 8; nt++) {
        short8 b0 = *(const short8*)(wb + (size_t)((nt * 2 + 0) * 64 + lane) * 8);
        short8 b1 = *(const short8*)(wb + (size_t)((nt * 2 + 1) * 64 + lane) * 8);
        acc[nt] = __builtin_amdgcn_mfma_f32_16x16x32_bf16(a[0], b0, acc[nt], 0, 0, 0);
        acc[nt] = __builtin_amdgcn_mfma_f32_16x16x32_bf16(a[1], b1, acc[nt], 0, 0, 0);
    }
    float bq[4];
#pragma unroll
    for (int nt = 0; nt < 4; nt++) bq[nt] = bg[nt * 16 + lm];
#pragma unroll
    for (int reg = 0; reg < 4; reg++) {
        int rown = wv * 16 + quad * 4 + reg;
#pragma unroll
        for (int nt = 0; nt < 4; nt++)
            outs[rown * 136 + nt * 16 + lm] = __float2half(acc[nt][reg]);
#pragma unroll
        for (int nt = 4; nt < 8; nt++)
            outs[rown * 136 + 64 + (nt - 4) * 16 + lm] = __float2half(acc[nt][reg] + bq[nt - 4]);
    }
    __syncthreads();
    int t = threadIdx.x;
#pragma unroll
    for (int r = 0; r < 4; r++) {
        int s = r * 256 + t;
        int node = s >> 4, seg = s & 15;
        int gn = nbase + node;
        if (gn < NND) {
            uint4 v = *(const uint4*)(outs + node * 136 + seg * 8);
            __half* dst = (seg < 8) ? (P16 + (size_t)gn * 64 + seg * 8)
                                    : (Q16 + (size_t)gn * 64 + (seg - 8) * 8);
            *(uint4*)dst = v;
        }
    }
}

// ---------------- fused aggregate + update ----------------
// 512 threads / 64 nodes. Gather: lane owns (node, feat8) -> walks CSR list directly,
// register accumulation, NO cross-lane ops. Then waves 0-3 do the MFMA update.
__global__ __launch_bounds__(512) void k_aggupd(float* __restrict__ x, const __half* __restrict__ P16,
                                                const __half* __restrict__ Q16,
                                                const int* __restrict__ row, const int* __restrict__ srcs,
                                                const short* __restrict__ wb, const float* __restrict__ ub,
                                                const float* __restrict__ lg, const float* __restrict__ lb) {
    __shared__ float aggs[64 * 68];
    int t = threadIdx.x, w = t >> 6, lane = t & 63;

    // ---- phase 1: gather (lane = node w*8+(lane>>3), feats (lane&7)*8..+7) ----
    {
        int ln = lane >> 3, f8 = lane & 7, c0 = f8 * 8;
        int bn = w * 8 + ln;
        int wid = blockIdx.x * 64 + bn;
        float acc[8];
#pragma unroll
        for (int k = 0; k < 8; k++) acc[k] = 0.f;
        if (wid < NND) {
            int beg = row[wid], end = row[wid + 1];
            float qv[8];
            load_h8(Q16 + (size_t)wid * 64 + c0, qv);
            int e = beg;
            for (; e + 2 <= end; e += 2) {
                int s0 = srcs[e], s1 = srcs[e + 1];
                float f0[8], f1[8];
                load_h8(P16 + (size_t)s0 * 64 + c0, f0);
                load_h8(P16 + (size_t)s1 * 64 + c0, f1);
#pragma unroll
                for (int k = 0; k < 8; k++) {
                    acc[k] += fmaxf(f0[k] + qv[k], 0.f);
                    acc[k] += fmaxf(f1[k] + qv[k], 0.f);
                }
            }
            if (e < end) {
                int s0 = srcs[e];
                float f0[8];
                load_h8(P16 + (size_t)s0 * 64 + c0, f0);
#pragma unroll
                for (int k = 0; k < 8; k++) acc[k] += fmaxf(f0[k] + qv[k], 0.f);
            }
            float inv = 1.f / fmaxf((float)(end - beg), 1.f);
            float4 o0 = make_float4(acc[0] * inv, acc[1] * inv, acc[2] * inv, acc[3] * inv);
            float4 o1 = make_float4(acc[4] * inv, acc[5] * inv, acc[6] * inv, acc[7] * inv);
            *(float4*)(aggs + bn * 68 + c0) = o0;
            *(float4*)(aggs + bn * 68 + c0 + 4) = o1;
        } else {
            *(float4*)(aggs + bn * 68 + c0) = make_float4(0.f, 0.f, 0.f, 0.f);
            *(float4*)(aggs + bn * 68 + c0 + 4) = make_float4(0.f, 0.f, 0.f, 0.f);
        }
    }
    __syncthreads();

    // ---- phase 2: MFMA update (waves 0-3 only, 16 nodes each) ----
    if (w >= 4) return;
    int lm = lane & 15, quad = lane >> 4;
    int gmbase = blockIdx.x * 64 + w * 16;
    int m = gmbase + lm;
    int bm = w * 16 + lm;
    short8 a[4];
#pragma unroll
    for (int ks = 0; ks < 2; ks++) {
        int c0 = ks * 32 + quad * 8;
        float xv[8];
        if (m < NND) {
            float4 v0 = *(const float4*)(x + (size_t)m * 64 + c0);
            float4 v1 = *(const float4*)(x + (size_t)m * 64 + c0 + 4);
            xv[0] = v0.x; xv[1] = v0.y; xv[2] = v0.z; xv[3] = v0.w;
            xv[4] = v1.x; xv[5] = v1.y; xv[6] = v1.z; xv[7] = v1.w;
        } else {
#pragma unroll
            for (int j = 0; j < 8; j++) xv[j] = 0.f;
        }
        short8 av;
#pragma unroll
        for (int j = 0; j < 8; j++) av[j] = f2bf(xv[j]);
        a[ks] = av;
    }
#pragma unroll
    for (int ks = 2; ks < 4; ks++) {
        const float* p = aggs + bm * 68 + (ks - 2) * 32 + quad * 8;
        float4 v0 = *(const float4*)p;
        float4 v1 = *(const float4*)(p + 4);
        float xv[8] = {v0.x, v0.y, v0.z, v0.w, v1.x, v1.y, v1.z, v1.w};
        short8 av;
#pragma unroll
        for (int j = 0; j < 8; j++) av[j] = f2bf(xv[j]);
        a[ks] = av;
    }
    floatx4 acc4[4];
#pragma unroll
    for (int nt = 0; nt < 4; nt++) acc4[nt] = (floatx4){0.f, 0.f, 0.f, 0.f};
#pragma unroll
    for (int nt = 0; nt < 4; nt++) {
#pragma unroll
        for (int ks = 0; ks < 4; ks++) {
            short8 b = *(const short8*)(wb + (size_t)((nt * 4 + ks) * 64 + lane) * 8);
            acc4[nt] = __builtin_amdgcn_mfma_f32_16x16x32_bf16(a[ks], b, acc4[nt], 0, 0, 0);
        }
    }
    float ubv[4], lgv[4], lbv[4];
#pragma unroll
    for (int nt = 0; nt < 4; nt++) {
        int col = nt * 16 + lm;
        ubv[nt] = ub[col]; lgv[nt] = lg[col]; lbv[nt] = lb[col];
    }
#pragma unroll
    for (int reg = 0; reg < 4; reg++) {
        int gn = gmbase + quad * 4 + reg;
        bool ok = gn < NND;
        float h[4];
#pragma unroll
        for (int nt = 0; nt < 4; nt++) {
            float xv = ok ? x[(size_t)gn * 64 + nt * 16 + lm] : 0.f;
            float u = fmaxf(acc4[nt][reg] + ubv[nt], 0.f);
            h[nt] = u + xv;
        }
        float s1 = h[0] + h[1] + h[2] + h[3];
        float s2 = h[0] * h[0] + h[1] * h[1] + h[2] * h[2] + h[3] * h[3];
#pragma unroll
        for (int off = 1; off < 16; off *= 2) {
            s1 += __shfl_xor(s1, off);
            s2 += __shfl_xor(s2, off);
        }
        float mu = s1 * (1.f / 64.f);
        float var = s2 * (1.f / 64.f) - mu * mu;
        float rs = rsqrtf(var + LNEPS);
        if (ok) {
#pragma unroll
            for (int nt = 0; nt < 4; nt++)
                x[(size_t)gn * 64 + nt * 16 + lm] = (h[nt] - mu) * rs * lgv[nt] + lbv[nt];
        }
    }
}

// ---------------- final reduce: column mean + max ----------------
__global__ void k_reduce(const float* __restrict__ x, float* __restrict__ rsum, unsigned* __restrict__ rmax) {
    __shared__ float sb[256];
    __shared__ float mb[256];
    int t = threadIdx.x;
    int j = t & 63, g = t >> 6;
    float s = 0.f, m = -3.402823466e38f;
    for (int r = blockIdx.x * 4 + g; r < NND; r += gridDim.x * 4) {
        float v = x[r * 64 + j];
        s += v;
        m = fmaxf(m, v);
    }
    sb[t] = s; mb[t] = m; __syncthreads();
    if (t < 64) {
        s = sb[t] + sb[t + 64] + sb[t + 128] + sb[t + 192];
        m = fmaxf(fmaxf(mb[t], mb[t + 64]), fmaxf(mb[t + 128], mb[t + 192]));
        atomicAdd(&rsum[j], s);
        unsigned b = __float_as_uint(m);
        unsigned enc = (b & 0x80000000u) ? ~b : (b | 0x80000000u);
        atomicMax(&rmax[j], enc);
    }
}

__global__ void k_fin(const float* __restrict__ rsum, const unsigned* __restrict__ rmax, float* __restrict__ out) {
    int t = threadIdx.x;
    if (t < 64) {
        out[t] = rsum[t] * (1.f / (float)NND);
    } else if (t < 128) {
        unsigned u = rmax[t - 64];
        unsigned b = (u & 0x80000000u) ? (u & 0x7fffffffu) : ~u;
        out[t] = __uint_as_float(b);
    }
}

extern "C" void kernel_launch(void* const* d_in, const int* in_sizes, int n_in,
                              void* d_out, int out_size, void* d_ws, size_t ws_size,
                              hipStream_t stream) {
    const int* ty      = (const int*)d_in[0];
    const int* ed      = (const int*)d_in[1];
    const float* tab   = (const float*)d_in[2];
    const float* msg_w = (const float*)d_in[3];
    const float* msg_b = (const float*)d_in[4];
    const float* upd_w = (const float*)d_in[5];
    const float* upd_b = (const float*)d_in[6];
    const float* ln_g  = (const float*)d_in[7];
    const float* ln_b  = (const float*)d_in[8];
    float* out = (float*)d_out;

    char* w = (char*)d_ws;
    auto alloc = [&](size_t sz) { char* p = w; w += (sz + 255) & ~(size_t)255; return p; };
    float* x       = (float*)alloc((size_t)NND * 64 * 4);
    __half* P16    = (__half*)alloc((size_t)NND * 64 * 2);
    __half* Q16    = (__half*)alloc((size_t)NND * 64 * 2);
    long long* tmp = (long long*)alloc((size_t)NED * 8);
    int* row       = (int*)alloc((size_t)(NND + 1) * 4);
    int* srcs      = (int*)alloc((size_t)NED * 4);
    int* bcnt      = (int*)alloc(256 * 4);
    int* bbase     = (int*)alloc(256 * 4);
    int* gtail     = (int*)alloc(256 * 4);
    float* rsum    = (float*)alloc(64 * 4);
    unsigned* rmax = (unsigned*)alloc(64 * 4);
    short* wmsg    = (short*)alloc((size_t)NLAY * 8192 * 2);
    short* wupd    = (short*)alloc((size_t)NLAY * 8192 * 2);

    k_init<<<2, 256, 0, stream>>>(bcnt, rsum, rmax);
    k_prep<<<(2 * NLAY * 8192 + 255) / 256, 256, 0, stream>>>(msg_w, upd_w, wmsg, wupd);
    k_embed<<<(NND * 16 + 255) / 256, 256, 0, stream>>>(ty, (const float4*)tab, (float4*)x);
    k_bhist<<<256, 256, 0, stream>>>((const int2*)ed, bcnt);
    k_bbase<<<1, 256, 0, stream>>>(bcnt, bbase, gtail);
    k_bscatter<<<(NED + 4095) / 4096, 256, 0, stream>>>((const int2*)ed, gtail, tmp);
    k_bfinish<<<NBKT, 512, 0, stream>>>(tmp, bbase, row, srcs);

    for (int l = 0; l < NLAY; l++) {
        k_pq<<<(NND + 63) / 64, 256, 0, stream>>>(x, wmsg + (size_t)l * 8192, msg_b + l * 64, P16, Q16);
        k_aggupd<<<(NND + 63) / 64, 512, 0, stream>>>(x, P16, Q16, row, srcs,
                                                      wupd + (size_t)l * 8192,
                                                      upd_b + l * 64, ln_g + l * 64, ln_b + l * 64);
    }
    k_reduce<<<256, 256, 0, stream>>>(x, rsum, rmax);
    k_fin<<<1, 128, 0, stream>>>(rsum, rmax, out);
}